// Round 3
// baseline (239.671 us; speedup 1.0000x reference)
//
#include <hip/hip_runtime.h>
#include <math.h>

#define B_ 8
#define T_ 64
#define N_ 196
#define D_ 768
#define K_ 8
#define FEAT 40
#define EPSF 1e-6f
#define CHUNK_B 2
#define NCHUNK (B_ / CHUNK_B)

constexpr int    ROWS   = B_ * T_ * N_;              // 100352
constexpr int    ROWS_C = CHUNK_B * T_ * N_;         // 25088
constexpr int    BN     = B_ * N_;                   // 1568
constexpr long long HSIZE = (long long)ROWS * D_;    // 77070336

typedef float v4f __attribute__((ext_vector_type(4)));

// ---- workspace layout (floats) ----
constexpr size_t WS_V     = 0;                       // [B,N,K,T] = 802816
constexpr size_t WS_Y     = 865536;                  // [BN,D]    = 1204224
constexpr size_t WS_BETAS = 2069760;                 // [D]       = 768

__device__ __forceinline__ float wredux(float v) {
#pragma unroll
    for (int off = 32; off > 0; off >>= 1)
        v += __shfl_xor(v, off, 64);
    return v;
}

// Kernel 1 (per chunk): v[b,n,k,t] = mask[b,t,n] * dot(x[b,t,n,:], proj_W[k,:])
// One wave per row, proj_W cached in 96 VGPRs, grid-stride over the chunk.
__global__ __launch_bounds__(256) void k_proj(const float* __restrict__ x,
                                              const float* __restrict__ mask,
                                              const float* __restrict__ pw,
                                              float* __restrict__ v_ws,
                                              int b0, int totalWaves) {
    const int lane = threadIdx.x & 63;
    const int gw   = blockIdx.x * (blockDim.x >> 6) + (threadIdx.x >> 6);
    const int base = b0 * T_ * N_;

    v4f u[3][8];
#pragma unroll
    for (int i = 0; i < 3; i++)
#pragma unroll
        for (int k = 0; k < 8; k++)
            u[i][k] = *(const v4f*)(pw + k * D_ + i * 256 + lane * 4);

    for (int r = gw; r < ROWS_C; r += totalWaves) {
        const int g = base + r;
        const v4f* xr = (const v4f*)(x + (size_t)g * D_);
        v4f xa = xr[lane];
        v4f xb = xr[lane + 64];
        v4f xc = xr[lane + 128];
        float acc[8];
#pragma unroll
        for (int k = 0; k < 8; k++) {
            float a;
            a  = xa.x * u[0][k].x + xa.y * u[0][k].y + xa.z * u[0][k].z + xa.w * u[0][k].w;
            a += xb.x * u[1][k].x + xb.y * u[1][k].y + xb.z * u[1][k].z + xb.w * u[1][k].w;
            a += xc.x * u[2][k].x + xc.y * u[2][k].y + xc.z * u[2][k].z + xc.w * u[2][k].w;
            acc[k] = wredux(a);
        }
        float m = mask[g];
        float val = acc[0];
#pragma unroll
        for (int k = 1; k < 8; k++)
            val = ((lane & 7) == k) ? acc[k] : val;
        if (lane < 8) {
            int b   = g / (T_ * N_);
            int rem = g - b * (T_ * N_);
            int t   = rem / N_;
            int n   = rem - t * N_;
            v_ws[(((size_t)(b * N_ + n)) * K_ + lane) * T_ + t] = val * m;
        }
    }
}

// Kernel 2 (per chunk): fused feat + tiny GEMM. One block per (b,n).
// 4 waves; wave w handles k=2w, 2w+1 (lane=t), writes 5 feats each to LDS;
// then all 256 threads do y[768] = feats[40] @ W[40,768].
__global__ __launch_bounds__(256) void k_fg(const float* __restrict__ v_ws,
                                            const float* __restrict__ W,
                                            float* __restrict__ y,
                                            int b0) {
    __shared__ float sf[FEAT];
    const int tid  = threadIdx.x;
    const int lane = tid & 63;
    const int w    = tid >> 6;
    const int bn   = b0 * N_ + blockIdx.x;

    const float PI = 3.14159265358979323846f;
    float ph = PI * ((float)lane + 0.5f) / (float)T_;
    float c1 = cosf(ph);
    float c2 = cosf(2.0f * ph);
    float n1 = wredux(c1 * c1);
    float n2 = wredux(c2 * c2);

#pragma unroll
    for (int kk = 0; kk < 2; kk++) {
        const int k = w * 2 + kk;
        float vv  = v_ws[((size_t)bn * K_ + k) * T_ + lane];
        float s2  = wredux(vv * vv);
        float rms = sqrtf(s2 * (1.0f / T_) + EPSF);
        float vb  = 2.5f * tanhf(vv / (rms + EPSF));
        float S1  = wredux(vb);
        float Sc1 = wredux(vb * c1);
        float Sc2 = wredux(vb * c2);
        float Sq  = wredux(vb * vb);
        if (lane == 0) {
            float* o = sf + k * 5;
            o[0] = S1 / (8.0f + EPSF);
            o[1] = Sc1 / (sqrtf(n1) + EPSF);
            o[2] = Sc2 / (sqrtf(n2) + EPSF);
            o[3] = S1 * (1.0f / T_);
            o[4] = sqrtf(Sq * (1.0f / T_) + EPSF);
        }
    }
    __syncthreads();

    float a0 = 0.f, a1 = 0.f, a2 = 0.f;
#pragma unroll
    for (int f = 0; f < FEAT; f++) {
        float s = sf[f];
        const float* wr = W + (size_t)f * D_;
        a0 += s * wr[tid];
        a1 += s * wr[tid + 256];
        a2 += s * wr[tid + 512];
    }
    float* yr = y + (size_t)bn * D_;
    yr[tid]       = a0;
    yr[tid + 256] = a1;
    yr[tid + 512] = a2;
}

// Kernel 3: W = softplus(W_raw) -> d_out tail;  beta_s = sigmoid(beta) -> ws
__global__ __launch_bounds__(256) void k_wsp(const float* __restrict__ wraw,
                                             const float* __restrict__ beta,
                                             float* __restrict__ wout,
                                             float* __restrict__ beta_s) {
    int i = blockIdx.x * blockDim.x + threadIdx.x;
    if (i < FEAT * D_) {
        float xw = wraw[i];
        wout[i] = fmaxf(xw, 0.0f) + log1pf(expf(-fabsf(xw)));
    }
    if (i < D_) beta_s[i] = 1.0f / (1.0f + expf(-beta[i]));
}

// Kernel 4 (per chunk): h = x + mask * beta_s * y.  Grid-stride, one v4f
// per thread-iter. x read should hit Infinity Cache (chunk still resident);
// h stored nontemporal so it doesn't evict the next chunk's x.
__global__ __launch_bounds__(256) void k_final(const float* __restrict__ x,
                                               const float* __restrict__ maskv,
                                               const float* __restrict__ y,
                                               const float* __restrict__ beta_s,
                                               float* __restrict__ h,
                                               int b0, int totalThreads) {
    constexpr int QPR = D_ / 4;                       // 192 v4f per row
    constexpr long long QTOT = (long long)ROWS_C * QPR;
    const long long qbase = (long long)b0 * T_ * N_ * QPR;
    const v4f* bs4 = (const v4f*)beta_s;
    const v4f* x4p = (const v4f*)x + qbase;
    const v4f* y4p = (const v4f*)y;
    v4f*       h4p = (v4f*)h + qbase;

    for (long long q = blockIdx.x * blockDim.x + threadIdx.x; q < QTOT;
         q += totalThreads) {
        int rowL = (int)(q / QPR);
        int d4   = (int)(q - (long long)rowL * QPR);
        int row  = b0 * T_ * N_ + rowL;
        int b    = row / (T_ * N_);
        int rem  = row - b * (T_ * N_);
        int n    = rem % N_;

        float m  = maskv[row];
        v4f   x4 = x4p[q];
        v4f   y4 = y4p[((size_t)(b * N_ + n)) * QPR + d4];
        v4f   b4 = bs4[d4];
        v4f   hv = x4 + m * b4 * y4;
        __builtin_nontemporal_store(hv, h4p + q);
    }
}

extern "C" void kernel_launch(void* const* d_in, const int* in_sizes, int n_in,
                              void* d_out, int out_size, void* d_ws, size_t ws_size,
                              hipStream_t stream) {
    const float* x    = (const float*)d_in[0];
    const float* mask = (const float*)d_in[1];
    const float* pw   = (const float*)d_in[2];
    const float* wraw = (const float*)d_in[3];
    const float* beta = (const float*)d_in[4];

    float* h    = (float*)d_out;
    float* wout = h + HSIZE;

    float* ws     = (float*)d_ws;
    float* v_ws   = ws + 0;
    float* y      = ws + WS_Y;
    float* beta_s = ws + WS_BETAS;

    hipLaunchKernelGGL(k_wsp, dim3((FEAT * D_ + 255) / 256), dim3(256), 0, stream,
                       wraw, beta, wout, beta_s);

    const int pblocks = 2048, pwaves = pblocks * 4;
    const int fblocks = 2048, fthreads = fblocks * 256;

    for (int c = 0; c < NCHUNK; c++) {
        const int b0 = c * CHUNK_B;
        hipLaunchKernelGGL(k_proj, dim3(pblocks), dim3(256), 0, stream,
                           x, mask, pw, v_ws, b0, pwaves);
        hipLaunchKernelGGL(k_fg, dim3(CHUNK_B * N_), dim3(256), 0, stream,
                           v_ws, wout, y, b0);
        hipLaunchKernelGGL(k_final, dim3(fblocks), dim3(256), 0, stream,
                           x, mask, y, beta_s, h, b0, fthreads);
    }
}